// Round 3
// baseline (204.075 us; speedup 1.0000x reference)
//
#include <hip/hip_runtime.h>
#include <hip/hip_bf16.h>

typedef short bf16x8 __attribute__((ext_vector_type(8)));
typedef float f32x4 __attribute__((ext_vector_type(4)));

#define H 128
#define L 512
#define CHUNK 64
#define NCHUNK (L / CHUNK)

__device__ inline unsigned short f2bf(float x) {
  unsigned int u = __float_as_uint(x);
  u += 0x7fff + ((u >> 16) & 1);  // round-to-nearest-even
  return (unsigned short)(u >> 16);
}

// ---- prep: u = W1 @ w_seed, v = W1 @ w_node, W2 -> bf16 ----
__global__ void prep_kernel(const float* __restrict__ w_seed,
                            const float* __restrict__ w_node,
                            const float* __restrict__ W1,
                            const float* __restrict__ W2,
                            float* __restrict__ uv,
                            unsigned short* __restrict__ w2bf) {
  const int t = threadIdx.x;
  const int b = blockIdx.x;
  if (b == 0) {
    const int j = t & 127;
    const float* wv = (t < 128) ? w_seed : w_node;
    float acc = 0.f;
    for (int k = 0; k < H; ++k) acc = fmaf(W1[j * H + k], wv[k], acc);
    uv[(t < 128 ? 0 : H) + j] = acc;
  } else {
    const int idx = (b - 1) * 256 + t;
    w2bf[idx] = f2bf(W2[idx]);
  }
}

// ---- fused main kernel: one block per batch segment ----
// 4 waves; wave w owns output-feature rows [32w, 32w+32) of layer 2.
// MFMA computes D[feature][node] (W2 as A, h1 as B) so each lane owns one
// node column -> score dot is in-lane FMA + 2-shfl reduce.
__global__ void __launch_bounds__(256, 4) fused_kernel(
    const float* __restrict__ xs, const float* __restrict__ xn,
    const float* __restrict__ b1v, const float* __restrict__ b2v,
    const float* __restrict__ wscore, const float* __restrict__ wstop,
    const int* __restrict__ indptr, const float* __restrict__ uvec,
    const unsigned short* __restrict__ w2bf, float* __restrict__ out) {
  __shared__ __align__(16) unsigned short hbuf[2][CHUNK * H];  // 2 x 16KB
  __shared__ __align__(16) float scores_s[L];                  // 2KB
  __shared__ float stop_s[H];
  __shared__ float red_s[8];
  __shared__ float s01[2];

  const int t = threadIdx.x;
  const int lane = t & 63;
  const int w = t >> 6;
  const int b = blockIdx.x;

  const int start = indptr[b * 3 + 0];
  const int mlen = indptr[b * 3 + 1] - start;
  const int clen = indptr[b * 3 + 2] - start;

  const int r16 = lane & 15, ko = lane >> 4;

  // ---- W2 A-fragments in registers: wave w's 32 feature rows, all K ----
  bf16x8 Wf[2][4];
#pragma unroll
  for (int ct = 0; ct < 2; ++ct)
#pragma unroll
    for (int ks = 0; ks < 4; ++ks)
      Wf[ct][ks] = *reinterpret_cast<const bf16x8*>(
          w2bf + (w * 32 + ct * 16 + r16) * H + ks * 32 + ko * 8);

  // gen constants: thread owns feature octet (t&15)
  const int koh = t & 15;
  const int rb = t >> 4;
  float u8[8], v8[8], c8[8];
#pragma unroll
  for (int e = 0; e < 8; ++e) {
    u8[e] = uvec[koh * 8 + e];
    v8[e] = uvec[H + koh * 8 + e];
    c8[e] = b1v[koh * 8 + e];
  }
  // epilogue constants: lane's features = w*32 + ct*16 + ko*4 + reg
  float wsr[2][4], b2r[2][4];
#pragma unroll
  for (int ct = 0; ct < 2; ++ct)
#pragma unroll
    for (int reg = 0; reg < 4; ++reg) {
      const int j = w * 32 + ct * 16 + ko * 4 + reg;
      wsr[ct][reg] = wscore[j];
      b2r[ct][reg] = b2v[j];
    }
  float stopacc[2][4] = {{0.f, 0.f, 0.f, 0.f}, {0.f, 0.f, 0.f, 0.f}};

  // zero the score accumulator (written via LDS atomics)
  scores_s[t] = 0.f;
  scores_s[t + 256] = 0.f;

  // hoisted swizzled LDS byte offsets (XOR operand is per-thread constant)
  const int mg = rb & 7;
  const int genoff = rb * 256 + ((koh ^ mg) << 4);
  const int mr = r16 & 7;
  int rdoff[4];
#pragma unroll
  for (int ks = 0; ks < 4; ++ks)
    rdoff[ks] = r16 * 256 + (((ks * 4 + ko) ^ mr) << 4);

  float xsr[4], xnr[4];

  auto gen_load = [&](int c) {
    const int pos0 = start + c * CHUNK + rb;
#pragma unroll
    for (int it = 0; it < 4; ++it) {
      xsr[it] = xs[pos0 + it * 16];
      xnr[it] = xn[pos0 + it * 16];
    }
  };

  auto gen_compute = [&](int c) {
    char* base = (char*)hbuf[c & 1] + genoff;
#pragma unroll
    for (int it = 0; it < 4; ++it) {
      const float xsv = xsr[it];
      const float xnv = xnr[it];
      union {
        bf16x8 v;
        __hip_bfloat162 h2[4];
      } pk;
#pragma unroll
      for (int e = 0; e < 4; ++e) {
        const float a0 = fmaf(xsv, u8[2 * e], fmaf(xnv, v8[2 * e], c8[2 * e]));
        const float a1 =
            fmaf(xsv, u8[2 * e + 1], fmaf(xnv, v8[2 * e + 1], c8[2 * e + 1]));
        const float s0 = __fdividef(a0, 1.f + __expf(-a0));
        const float s1 = __fdividef(a1, 1.f + __expf(-a1));
        float2 f2;
        f2.x = s0;
        f2.y = s1;
        pk.h2[e] = __float22bfloat162_rn(f2);
      }
      *reinterpret_cast<bf16x8*>(base + it * 4096) = pk.v;
    }
  };

  // MFMA layer-2 + fused swish/score/stop epilogue.
  // MC = 2: chunk fully inside mean window; 1: straddles; 0: outside.
  auto mma = [&](int c, auto mc_tag) {
    constexpr int MC = decltype(mc_tag)::value;
    const char* base = (const char*)hbuf[c & 1];
#pragma unroll
    for (int rt = 0; rt < 4; ++rt) {
      bf16x8 Hf[4];
#pragma unroll
      for (int ks = 0; ks < 4; ++ks)
        Hf[ks] =
            *reinterpret_cast<const bf16x8*>(base + rdoff[ks] + rt * 4096);
      const int nodeg = c * CHUNK + rt * 16 + r16;
      const bool in = (MC == 1) ? (nodeg < mlen) : (MC == 2);
      float p = 0.f;
#pragma unroll
      for (int ct = 0; ct < 2; ++ct) {
        f32x4 acc = {0.f, 0.f, 0.f, 0.f};
#pragma unroll
        for (int ks = 0; ks < 4; ++ks)
          acc = __builtin_amdgcn_mfma_f32_16x16x32_bf16(Wf[ct][ks], Hf[ks],
                                                        acc, 0, 0, 0);
#pragma unroll
        for (int reg = 0; reg < 4; ++reg) {
          const float pre = acc[reg] + b2r[ct][reg];
          const float h2 = __fdividef(pre, 1.f + __expf(-pre));
          p = fmaf(h2, wsr[ct][reg], p);
          if (MC != 0) stopacc[ct][reg] += in ? h2 : 0.f;
        }
      }
      // sum this wave's 32 features: in-lane done; fold the 4 ko groups
      p += __shfl_xor(p, 16, 64);
      p += __shfl_xor(p, 32, 64);
      if (lane < 16) atomicAdd(&scores_s[nodeg], p);
    }
  };

  gen_load(0);
  gen_compute(0);
  __syncthreads();
#pragma unroll 1
  for (int c = 0; c < NCHUNK; ++c) {
    if (c + 1 < NCHUNK) gen_load(c + 1);
    const int cb = c * CHUNK;
    if (cb + CHUNK <= mlen)
      mma(c, std::integral_constant<int, 2>{});
    else if (cb >= mlen)
      mma(c, std::integral_constant<int, 0>{});
    else
      mma(c, std::integral_constant<int, 1>{});
    if (c + 1 < NCHUNK) gen_compute(c + 1);
    __syncthreads();
  }

  // ---- stop-feature reduction: fold 16 node-columns per lane group ----
#pragma unroll
  for (int ct = 0; ct < 2; ++ct)
#pragma unroll
    for (int reg = 0; reg < 4; ++reg) {
      float s = stopacc[ct][reg];
      s += __shfl_xor(s, 1, 64);
      s += __shfl_xor(s, 2, 64);
      s += __shfl_xor(s, 4, 64);
      s += __shfl_xor(s, 8, 64);
      if (r16 == 0) stop_s[w * 32 + ct * 16 + ko * 4 + reg] = s;
    }
  __syncthreads();

  // ---- stop head: 2-class log-softmax (wave 0) ----
  if (w == 0) {
    const float inv = __fdividef(1.f, (float)mlen);
    const float sn0 = stop_s[lane] * inv;
    const float sn1 = stop_s[lane + 64] * inv;
    float z0 = sn0 * wstop[lane] + sn1 * wstop[lane + 64];
    float z1 = sn0 * wstop[H + lane] + sn1 * wstop[H + lane + 64];
#pragma unroll
    for (int m = 1; m < 64; m <<= 1) {
      z0 += __shfl_xor(z0, m, 64);
      z1 += __shfl_xor(z1, m, 64);
    }
    if (lane == 0) {
      const float mx = fmaxf(z0, z1);
      const float lse = mx + __logf(__expf(z0 - mx) + __expf(z1 - mx));
      s01[0] = z0 - lse;
      s01[1] = z1 - lse;
      out[(size_t)b * (L + 1) + L] = z1 - lse;
    }
  }
  __syncthreads();

  // ---- node log-softmax over 512 scores ----
  float v0 = (t < clen) ? scores_s[t] : -__builtin_inff();
  float v1 = (t + 256 < clen) ? scores_s[t + 256] : -__builtin_inff();
  float mx = fmaxf(v0, v1);
#pragma unroll
  for (int m = 1; m < 64; m <<= 1) mx = fmaxf(mx, __shfl_xor(mx, m, 64));
  if (lane == 0) red_s[w] = mx;
  __syncthreads();
  mx = fmaxf(fmaxf(red_s[0], red_s[1]), fmaxf(red_s[2], red_s[3]));
  float sm = __expf(v0 - mx) + __expf(v1 - mx);
#pragma unroll
  for (int m = 1; m < 64; m <<= 1) sm += __shfl_xor(sm, m, 64);
  if (lane == 0) red_s[4 + w] = sm;
  __syncthreads();
  const float tot = red_s[4] + red_s[5] + red_s[6] + red_s[7];
  const float lse2 = mx + __logf(tot);
  const float addv = s01[0];
  out[(size_t)b * (L + 1) + t] = v0 - lse2 + addv;
  out[(size_t)b * (L + 1) + 256 + t] = v1 - lse2 + addv;
}

extern "C" void kernel_launch(void* const* d_in, const int* in_sizes, int n_in,
                              void* d_out, int out_size, void* d_ws,
                              size_t ws_size, hipStream_t stream) {
  const float* x_seeds = (const float*)d_in[0];
  const float* x_nodes = (const float*)d_in[1];
  const float* w_seed = (const float*)d_in[2];
  const float* w_node = (const float*)d_in[3];
  const float* W1 = (const float*)d_in[4];
  const float* b1 = (const float*)d_in[5];
  const float* W2 = (const float*)d_in[6];
  const float* b2 = (const float*)d_in[7];
  const float* w_score = (const float*)d_in[8];
  const float* W_stop = (const float*)d_in[9];
  const int* indptr = (const int*)d_in[10];

  const int B = in_sizes[10] / 3;
  float* uv = (float*)d_ws;
  unsigned short* w2bf = (unsigned short*)((char*)d_ws + 1024);

  hipLaunchKernelGGL(prep_kernel, dim3(1 + (H * H) / 256), dim3(256), 0,
                     stream, w_seed, w_node, W1, W2, uv, w2bf);
  hipLaunchKernelGGL(fused_kernel, dim3(B), dim3(256), 0, stream, x_seeds,
                     x_nodes, b1, b2, w_score, W_stop, indptr, uv, w2bf,
                     (float*)d_out);
}

// Round 4
// 178.514 us; speedup vs baseline: 1.1432x; 1.1432x over previous
//
#include <hip/hip_runtime.h>
#include <hip/hip_bf16.h>

typedef short bf16x8 __attribute__((ext_vector_type(8)));
typedef float f32x4 __attribute__((ext_vector_type(4)));

#define H 128
#define L 512
#define CHUNK 64
#define NCHUNK (L / CHUNK)

__device__ inline unsigned short f2bf(float x) {
  unsigned int u = __float_as_uint(x);
  u += 0x7fff + ((u >> 16) & 1);  // round-to-nearest-even
  return (unsigned short)(u >> 16);
}

// ---- prep: u = W1 @ w_seed, v = W1 @ w_node, W2 -> bf16 ----
__global__ void prep_kernel(const float* __restrict__ w_seed,
                            const float* __restrict__ w_node,
                            const float* __restrict__ W1,
                            const float* __restrict__ W2,
                            float* __restrict__ uv,
                            unsigned short* __restrict__ w2bf) {
  const int t = threadIdx.x;
  const int b = blockIdx.x;
  if (b == 0) {
    const int j = t & 127;
    const float* wv = (t < 128) ? w_seed : w_node;
    float acc = 0.f;
    for (int k = 0; k < H; ++k) acc = fmaf(W1[j * H + k], wv[k], acc);
    uv[(t < 128 ? 0 : H) + j] = acc;
  } else {
    const int idx = (b - 1) * 256 + t;
    w2bf[idx] = f2bf(W2[idx]);
  }
}

// ---- fused main kernel: one block per batch segment ----
// 4 waves; wave w owns output-feature rows [32w, 32w+32) of layer 2.
// MFMA computes D[feature][node] (W2 as A, h1 as B) so each lane owns one
// node column -> score dot is in-lane FMA + 2 shfl + 1 LDS atomic per rt.
// gen stays fused (load->compute->store) per R3 post-mortem: holding loads
// across the mma call spilled to scratch (FETCH 16->55MB) and regressed.
__global__ void __launch_bounds__(256, 4) fused_kernel(
    const float* __restrict__ xs, const float* __restrict__ xn,
    const float* __restrict__ b1v, const float* __restrict__ b2v,
    const float* __restrict__ wscore, const float* __restrict__ wstop,
    const int* __restrict__ indptr, const float* __restrict__ uvec,
    const unsigned short* __restrict__ w2bf, float* __restrict__ out) {
  __shared__ __align__(16) unsigned short hbuf[2][CHUNK * H];  // 2 x 16KB
  __shared__ __align__(16) float scores_s[L];                  // 2KB
  __shared__ float stop_s[H];
  __shared__ float red_s[8];
  __shared__ float s01[2];

  const int t = threadIdx.x;
  const int lane = t & 63;
  const int w = t >> 6;
  const int b = blockIdx.x;

  const int start = indptr[b * 3 + 0];
  const int mlen = indptr[b * 3 + 1] - start;
  const int clen = indptr[b * 3 + 2] - start;

  const int r16 = lane & 15, ko = lane >> 4;

  // ---- W2 A-fragments in registers: wave w's 32 feature rows, all K ----
  bf16x8 Wf[2][4];
#pragma unroll
  for (int ct = 0; ct < 2; ++ct)
#pragma unroll
    for (int ks = 0; ks < 4; ++ks)
      Wf[ct][ks] = *reinterpret_cast<const bf16x8*>(
          w2bf + (w * 32 + ct * 16 + r16) * H + ks * 32 + ko * 8);

  // gen constants: thread owns feature octet (t&15)
  const int koh = t & 15;
  const int rb = t >> 4;
  float u8[8], v8[8], c8[8];
#pragma unroll
  for (int e = 0; e < 8; ++e) {
    u8[e] = uvec[koh * 8 + e];
    v8[e] = uvec[H + koh * 8 + e];
    c8[e] = b1v[koh * 8 + e];
  }
  // epilogue constants: lane's features = w*32 + ct*16 + ko*4 + reg
  float wsr[2][4], b2r[2][4];
#pragma unroll
  for (int ct = 0; ct < 2; ++ct)
#pragma unroll
    for (int reg = 0; reg < 4; ++reg) {
      const int j = w * 32 + ct * 16 + ko * 4 + reg;
      wsr[ct][reg] = wscore[j];
      b2r[ct][reg] = b2v[j];
    }
  float stopacc[2][4] = {{0.f, 0.f, 0.f, 0.f}, {0.f, 0.f, 0.f, 0.f}};

  // zero the score accumulator (written via LDS atomics)
  scores_s[t] = 0.f;
  scores_s[t + 256] = 0.f;

  // hoisted swizzled LDS byte offsets (XOR operand is per-thread constant)
  const int genoff = rb * 256 + ((koh ^ (rb & 7)) << 4);
  const int mr = r16 & 7;
  int rdoff[4];
#pragma unroll
  for (int ks = 0; ks < 4; ++ks)
    rdoff[ks] = r16 * 256 + (((ks * 4 + ko) ^ mr) << 4);

  // generate h1 = swish(xs*u + xn*v + b1) in bf16 into swizzled LDS tile
  auto gen = [&](int c) {
    char* base = (char*)hbuf[c & 1] + genoff;
    const int pos0 = start + c * CHUNK + rb;
#pragma unroll
    for (int it = 0; it < 4; ++it) {
      const float xsv = xs[pos0 + it * 16];
      const float xnv = xn[pos0 + it * 16];
      union {
        bf16x8 v;
        __hip_bfloat162 h2[4];
      } pk;
#pragma unroll
      for (int e = 0; e < 4; ++e) {
        const float a0 = fmaf(xsv, u8[2 * e], fmaf(xnv, v8[2 * e], c8[2 * e]));
        const float a1 =
            fmaf(xsv, u8[2 * e + 1], fmaf(xnv, v8[2 * e + 1], c8[2 * e + 1]));
        const float s0 = __fdividef(a0, 1.f + __expf(-a0));
        const float s1 = __fdividef(a1, 1.f + __expf(-a1));
        float2 f2;
        f2.x = s0;
        f2.y = s1;
        pk.h2[e] = __float22bfloat162_rn(f2);
      }
      *reinterpret_cast<bf16x8*>(base + it * 4096) = pk.v;
    }
  };

  // MFMA layer-2 + fused swish/score/stop epilogue.
  // MC = 2: chunk fully inside mean window; 1: straddles; 0: outside.
  auto mma = [&](int c, auto mc_tag) {
    constexpr int MC = decltype(mc_tag)::value;
    const char* base = (const char*)hbuf[c & 1];
#pragma unroll
    for (int rt = 0; rt < 4; ++rt) {
      bf16x8 Hf[4];
#pragma unroll
      for (int ks = 0; ks < 4; ++ks)
        Hf[ks] =
            *reinterpret_cast<const bf16x8*>(base + rdoff[ks] + rt * 4096);
      const int nodeg = c * CHUNK + rt * 16 + r16;
      const bool in = (MC == 1) ? (nodeg < mlen) : (MC == 2);
      float p = 0.f;
#pragma unroll
      for (int ct = 0; ct < 2; ++ct) {
        f32x4 acc = {0.f, 0.f, 0.f, 0.f};
#pragma unroll
        for (int ks = 0; ks < 4; ++ks)
          acc = __builtin_amdgcn_mfma_f32_16x16x32_bf16(Wf[ct][ks], Hf[ks],
                                                        acc, 0, 0, 0);
#pragma unroll
        for (int reg = 0; reg < 4; ++reg) {
          const float pre = acc[reg] + b2r[ct][reg];
          const float h2 = __fdividef(pre, 1.f + __expf(-pre));
          p = fmaf(h2, wsr[ct][reg], p);
          if (MC != 0) stopacc[ct][reg] += in ? h2 : 0.f;
        }
      }
      // sum this wave's 32 features: in-lane done; fold the 4 ko groups
      p += __shfl_xor(p, 16, 64);
      p += __shfl_xor(p, 32, 64);
      if (lane < 16) atomicAdd(&scores_s[nodeg], p);
    }
  };

  gen(0);
  __syncthreads();
#pragma unroll 1
  for (int c = 0; c < NCHUNK; ++c) {
    if (c + 1 < NCHUNK) gen(c + 1);
    const int cb = c * CHUNK;
    if (cb + CHUNK <= mlen)
      mma(c, std::integral_constant<int, 2>{});
    else if (cb >= mlen)
      mma(c, std::integral_constant<int, 0>{});
    else
      mma(c, std::integral_constant<int, 1>{});
    __syncthreads();
  }

  // ---- stop-feature reduction: fold 16 node-columns per lane group ----
#pragma unroll
  for (int ct = 0; ct < 2; ++ct)
#pragma unroll
    for (int reg = 0; reg < 4; ++reg) {
      float s = stopacc[ct][reg];
      s += __shfl_xor(s, 1, 64);
      s += __shfl_xor(s, 2, 64);
      s += __shfl_xor(s, 4, 64);
      s += __shfl_xor(s, 8, 64);
      if (r16 == 0) stop_s[w * 32 + ct * 16 + ko * 4 + reg] = s;
    }
  __syncthreads();

  // ---- stop head: 2-class log-softmax (wave 0) ----
  if (w == 0) {
    const float inv = __fdividef(1.f, (float)mlen);
    const float sn0 = stop_s[lane] * inv;
    const float sn1 = stop_s[lane + 64] * inv;
    float z0 = sn0 * wstop[lane] + sn1 * wstop[lane + 64];
    float z1 = sn0 * wstop[H + lane] + sn1 * wstop[H + lane + 64];
#pragma unroll
    for (int m = 1; m < 64; m <<= 1) {
      z0 += __shfl_xor(z0, m, 64);
      z1 += __shfl_xor(z1, m, 64);
    }
    if (lane == 0) {
      const float mx = fmaxf(z0, z1);
      const float lse = mx + __logf(__expf(z0 - mx) + __expf(z1 - mx));
      s01[0] = z0 - lse;
      s01[1] = z1 - lse;
      out[(size_t)b * (L + 1) + L] = z1 - lse;
    }
  }
  __syncthreads();

  // ---- node log-softmax over 512 scores ----
  float v0 = (t < clen) ? scores_s[t] : -__builtin_inff();
  float v1 = (t + 256 < clen) ? scores_s[t + 256] : -__builtin_inff();
  float mx = fmaxf(v0, v1);
#pragma unroll
  for (int m = 1; m < 64; m <<= 1) mx = fmaxf(mx, __shfl_xor(mx, m, 64));
  if (lane == 0) red_s[w] = mx;
  __syncthreads();
  mx = fmaxf(fmaxf(red_s[0], red_s[1]), fmaxf(red_s[2], red_s[3]));
  float sm = __expf(v0 - mx) + __expf(v1 - mx);
#pragma unroll
  for (int m = 1; m < 64; m <<= 1) sm += __shfl_xor(sm, m, 64);
  if (lane == 0) red_s[4 + w] = sm;
  __syncthreads();
  const float tot = red_s[4] + red_s[5] + red_s[6] + red_s[7];
  const float lse2 = mx + __logf(tot);
  const float addv = s01[0];
  out[(size_t)b * (L + 1) + t] = v0 - lse2 + addv;
  out[(size_t)b * (L + 1) + 256 + t] = v1 - lse2 + addv;
}

extern "C" void kernel_launch(void* const* d_in, const int* in_sizes, int n_in,
                              void* d_out, int out_size, void* d_ws,
                              size_t ws_size, hipStream_t stream) {
  const float* x_seeds = (const float*)d_in[0];
  const float* x_nodes = (const float*)d_in[1];
  const float* w_seed = (const float*)d_in[2];
  const float* w_node = (const float*)d_in[3];
  const float* W1 = (const float*)d_in[4];
  const float* b1 = (const float*)d_in[5];
  const float* W2 = (const float*)d_in[6];
  const float* b2 = (const float*)d_in[7];
  const float* w_score = (const float*)d_in[8];
  const float* W_stop = (const float*)d_in[9];
  const int* indptr = (const int*)d_in[10];

  const int B = in_sizes[10] / 3;
  float* uv = (float*)d_ws;
  unsigned short* w2bf = (unsigned short*)((char*)d_ws + 1024);

  hipLaunchKernelGGL(prep_kernel, dim3(1 + (H * H) / 256), dim3(256), 0,
                     stream, w_seed, w_node, W1, W2, uv, w2bf);
  hipLaunchKernelGGL(fused_kernel, dim3(B), dim3(256), 0, stream, x_seeds,
                     x_nodes, b1, b2, w_score, W_stop, indptr, uv, w2bf,
                     (float*)d_out);
}

// Round 5
// 33.423 us; speedup vs baseline: 6.1057x; 5.3410x over previous
//
#include <hip/hip_runtime.h>

#define H 128
#define L 512
#define KN 65           // knots per axis (64 cells)
#define NKN (KN * KN)   // 4225
#define RNG 6.0f        // table spans [-RNG, RNG] per axis

__device__ inline unsigned short f2bf(float x) {
  unsigned int u = __float_as_uint(x);
  u += 0x7fff + ((u >> 16) & 1);  // round-to-nearest-even
  return (unsigned short)(u >> 16);
}

__device__ inline float swishf(float a) { return __fdividef(a, 1.f + __expf(-a)); }

// ---- kernel 1: u = W1 @ w_seed, v = W1 @ w_node (1 block; W1 staged+swizzled) ----
__global__ void __launch_bounds__(256) prep_uv(
    const float* __restrict__ w_seed, const float* __restrict__ w_node,
    const float* __restrict__ W1, float* __restrict__ uv) {
  __shared__ __align__(16) char w1s[H * 512];
  const int t = threadIdx.x;
  for (int i = t; i < H * 32; i += 256) {
    const int row = i >> 5, k = i & 31;
    const float4 v = *reinterpret_cast<const float4*>(W1 + row * H + k * 4);
    *reinterpret_cast<float4*>(w1s + row * 512 + ((k * 16) ^ ((row & 7) << 4))) = v;
  }
  __syncthreads();
  const int j = t & 127;
  const float* wv = (t < 128) ? w_seed : w_node;
  const char* rbase = w1s + j * 512;
  const int sw = (j & 7) << 4;
  float acc = 0.f;
  for (int k = 0; k < 32; ++k) {
    const float4 a = *reinterpret_cast<const float4*>(rbase + ((k * 16) ^ sw));
    acc = fmaf(a.x, wv[k * 4 + 0],
          fmaf(a.y, wv[k * 4 + 1],
          fmaf(a.z, wv[k * 4 + 2], fmaf(a.w, wv[k * 4 + 3], acc))));
  }
  uv[(t < 128 ? 0 : H) + j] = acc;
}

// ---- kernel 2: build the 65x65 table of {F, packed(G0,G1)} ----
// One wave per knot (xa, xb): full f32 MLP eval, exact reference math.
// F = wscore . h2 ; Gc = W_stop[c,:] . h2 (mean commutes with the dot).
__global__ void __launch_bounds__(256, 2) build_tables(
    const float* __restrict__ uv, const float* __restrict__ b1v,
    const float* __restrict__ W2, const float* __restrict__ b2v,
    const float* __restrict__ wscore, const float* __restrict__ wstop,
    float2* __restrict__ tab) {
  __shared__ __align__(16) char w2s[H * 512];  // 64KB, XOR-swizzled rows
  __shared__ float h1s[4][H];
  const int t = threadIdx.x, lane = t & 63, w = t >> 6;
  for (int i = t; i < H * 32; i += 256) {
    const int row = i >> 5, k = i & 31;
    const float4 v = *reinterpret_cast<const float4*>(W2 + row * H + k * 4);
    *reinterpret_cast<float4*>(w2s + row * 512 + ((k * 16) ^ ((row & 7) << 4))) = v;
  }
  __syncthreads();
  const int p = blockIdx.x * 4 + w;
  const bool act = p < NKN;
  const int pp = act ? p : 0;
  const int iy = pp / KN, ix = pp - iy * KN;
  const float step = 2.f * RNG / (KN - 1);
  const float xa = -RNG + ix * step;
  const float xb = -RNG + iy * step;
  // layer 1 for this wave's point (each lane: features lane, lane+64)
  {
    const float a0 = fmaf(xa, uv[lane], fmaf(xb, uv[H + lane], b1v[lane]));
    const float a1 =
        fmaf(xa, uv[lane + 64], fmaf(xb, uv[H + lane + 64], b1v[lane + 64]));
    h1s[w][lane] = swishf(a0);
    h1s[w][lane + 64] = swishf(a1);
  }
  // layer 2: lane owns rows lane, lane+64 of W2
  float preA = b2v[lane], preB = b2v[lane + 64];
  const char* rA = w2s + lane * 512;
  const char* rB = w2s + (lane + 64) * 512;
  const int sw = (lane & 7) << 4;
  for (int k = 0; k < 32; ++k) {
    const float4 h1v = *reinterpret_cast<const float4*>(&h1s[w][k * 4]);
    const float4 wa = *reinterpret_cast<const float4*>(rA + ((k * 16) ^ sw));
    const float4 wb = *reinterpret_cast<const float4*>(rB + ((k * 16) ^ sw));
    preA = fmaf(wa.x, h1v.x, fmaf(wa.y, h1v.y, fmaf(wa.z, h1v.z, fmaf(wa.w, h1v.w, preA))));
    preB = fmaf(wb.x, h1v.x, fmaf(wb.y, h1v.y, fmaf(wb.z, h1v.z, fmaf(wb.w, h1v.w, preB))));
  }
  const float hA = swishf(preA), hB = swishf(preB);
  float F = fmaf(hA, wscore[lane], hB * wscore[lane + 64]);
  float G0 = fmaf(hA, wstop[lane], hB * wstop[lane + 64]);
  float G1 = fmaf(hA, wstop[H + lane], hB * wstop[H + lane + 64]);
#pragma unroll
  for (int m = 1; m < 64; m <<= 1) {
    F += __shfl_xor(F, m, 64);
    G0 += __shfl_xor(G0, m, 64);
    G1 += __shfl_xor(G1, m, 64);
  }
  if (act && lane == 0) {
    const unsigned pk = ((unsigned)f2bf(G1) << 16) | (unsigned)f2bf(G0);
    tab[p] = make_float2(F, __uint_as_float(pk));
  }
}

// ---- kernel 3: one wave per batch; bilinear lookups + softmax heads ----
__global__ void __launch_bounds__(256) main_kernel(
    const float* __restrict__ xs, const float* __restrict__ xn,
    const int* __restrict__ indptr, const float2* __restrict__ tab,
    float* __restrict__ out, int B) {
  __shared__ __align__(16) float2 tabs[NKN];  // 33.8KB
  const int t = threadIdx.x, lane = t & 63, w = t >> 6;
  for (int i = t; i < NKN; i += 256) tabs[i] = tab[i];
  __syncthreads();
  const int b = blockIdx.x * 4 + w;
  if (b >= B) return;
  const int s0 = indptr[b * 3];
  const int mlen = indptr[b * 3 + 1] - s0;
  const int clen = indptr[b * 3 + 2] - s0;
  constexpr float SC = (KN - 1) / (2.f * RNG);
  const float FMAXI = (float)(KN - 1) - 0.001f;
  float sc[8];
  float ga0 = 0.f, ga1 = 0.f;
#pragma unroll
  for (int i = 0; i < 8; ++i) {
    const int pos = lane + i * 64;
    const float x = xs[s0 + pos];
    const float y = xn[s0 + pos];
    const float fx = fminf(fmaxf(fmaf(x, SC, RNG * SC), 0.f), FMAXI);
    const float fy = fminf(fmaxf(fmaf(y, SC, RNG * SC), 0.f), FMAXI);
    const int ixi = (int)fx, iyi = (int)fy;
    const float ax = fx - (float)ixi, ay = fy - (float)iyi;
    const int idx = iyi * KN + ixi;
    const float2 v00 = tabs[idx];
    const float2 v01 = tabs[idx + 1];
    const float2 v10 = tabs[idx + KN];
    const float2 v11 = tabs[idx + KN + 1];
    // F bilinear
    const float Ft = fmaf(ax, v01.x - v00.x, v00.x);
    const float Fb = fmaf(ax, v11.x - v10.x, v10.x);
    const float Fv = fmaf(ay, Fb - Ft, Ft);
    // G0/G1 unpack (bf16 pair) + bilinear
    const unsigned u00 = __float_as_uint(v00.y), u01 = __float_as_uint(v01.y);
    const unsigned u10 = __float_as_uint(v10.y), u11 = __float_as_uint(v11.y);
    const float g000 = __uint_as_float(u00 << 16), g100 = __uint_as_float(u00 & 0xffff0000u);
    const float g001 = __uint_as_float(u01 << 16), g101 = __uint_as_float(u01 & 0xffff0000u);
    const float g010 = __uint_as_float(u10 << 16), g110 = __uint_as_float(u10 & 0xffff0000u);
    const float g011 = __uint_as_float(u11 << 16), g111 = __uint_as_float(u11 & 0xffff0000u);
    const float g0t = fmaf(ax, g001 - g000, g000);
    const float g0b = fmaf(ax, g011 - g010, g010);
    const float g0v = fmaf(ay, g0b - g0t, g0t);
    const float g1t = fmaf(ax, g101 - g100, g100);
    const float g1b = fmaf(ax, g111 - g110, g110);
    const float g1v = fmaf(ay, g1b - g1t, g1t);
    sc[i] = (pos < clen) ? Fv : -__builtin_inff();
    if (pos < mlen) {
      ga0 += g0v;
      ga1 += g1v;
    }
  }
  // stop head: masked mean of g0,g1 -> 2-class log-softmax
#pragma unroll
  for (int m = 1; m < 64; m <<= 1) {
    ga0 += __shfl_xor(ga0, m, 64);
    ga1 += __shfl_xor(ga1, m, 64);
  }
  const float inv = __fdividef(1.f, (float)mlen);
  const float z0 = ga0 * inv, z1 = ga1 * inv;
  const float mz = fmaxf(z0, z1);
  const float lses = mz + __logf(__expf(z0 - mz) + __expf(z1 - mz));
  const float sl0 = z0 - lses, sl1 = z1 - lses;
  // node log-softmax over 512 scores
  float mx = sc[0];
#pragma unroll
  for (int i = 1; i < 8; ++i) mx = fmaxf(mx, sc[i]);
#pragma unroll
  for (int m = 1; m < 64; m <<= 1) mx = fmaxf(mx, __shfl_xor(mx, m, 64));
  float sm = 0.f;
#pragma unroll
  for (int i = 0; i < 8; ++i) sm += __expf(sc[i] - mx);
#pragma unroll
  for (int m = 1; m < 64; m <<= 1) sm += __shfl_xor(sm, m, 64);
  const float base = sl0 - (mx + __logf(sm));
  float* orow = out + (size_t)b * (L + 1);
#pragma unroll
  for (int i = 0; i < 8; ++i) orow[lane + i * 64] = sc[i] + base;
  if (lane == 0) orow[L] = sl1;
}

extern "C" void kernel_launch(void* const* d_in, const int* in_sizes, int n_in,
                              void* d_out, int out_size, void* d_ws,
                              size_t ws_size, hipStream_t stream) {
  const float* x_seeds = (const float*)d_in[0];
  const float* x_nodes = (const float*)d_in[1];
  const float* w_seed = (const float*)d_in[2];
  const float* w_node = (const float*)d_in[3];
  const float* W1 = (const float*)d_in[4];
  const float* b1 = (const float*)d_in[5];
  const float* W2 = (const float*)d_in[6];
  const float* b2 = (const float*)d_in[7];
  const float* w_score = (const float*)d_in[8];
  const float* W_stop = (const float*)d_in[9];
  const int* indptr = (const int*)d_in[10];

  const int B = in_sizes[10] / 3;
  float* uv = (float*)d_ws;
  float2* tab = (float2*)((char*)d_ws + 1024);

  hipLaunchKernelGGL(prep_uv, dim3(1), dim3(256), 0, stream, w_seed, w_node,
                     W1, uv);
  hipLaunchKernelGGL(build_tables, dim3((NKN + 3) / 4), dim3(256), 0, stream,
                     uv, b1, W2, b2, w_score, W_stop, tab);
  hipLaunchKernelGGL(main_kernel, dim3((B + 3) / 4), dim3(256), 0, stream,
                     x_seeds, x_nodes, indptr, tab, (float*)d_out, B);
}